// Round 8
// baseline (135.495 us; speedup 1.0000x reference)
//
#include <hip/hip_runtime.h>
#include <math.h>

// Problem constants
#define DIM   256
#define NST   256
#define LSEQ  512
#define BAT   2
#define DTSZ  64
#define PCOLS 576
#define NROWS 1024

constexpr float LOG2E = 1.4426950408889634f;

__device__ __forceinline__ float fexp2(float v) {
#if __has_builtin(__builtin_amdgcn_exp2f)
    return __builtin_amdgcn_exp2f(v);
#else
    return exp2f(v);
#endif
}

__device__ __forceinline__ float softplusf(float v) {
    return (v > 20.f) ? v : log1pf(__expf(v));
}

// ---------------- proj: x@W_in (+ dt GEMM + softplus + dt*x). 512 blocks x 256.
// (unchanged from round 6/7 — don't churn a working kernel)
__global__ __launch_bounds__(256) void proj_kernel(
    const float* __restrict__ x, const float* __restrict__ W_in,
    const float* __restrict__ W_dt, const float* __restrict__ b_dt,
    float* __restrict__ bet, float* __restrict__ gam,
    float* __restrict__ dtp, float* __restrict__ dtxp)
{
    __shared__ float xs[2][DIM];
    __shared__ float draw[2][DTSZ];
    const int j = threadIdx.x;
    const int row0 = blockIdx.x * 2;

    #pragma unroll
    for (int r = 0; r < 2; ++r) xs[r][j] = x[(row0 + r) * DIM + j];
    __syncthreads();

    float acc0[2] = {0.f, 0.f}, acc1[2] = {0.f, 0.f}, acc2[2] = {0.f, 0.f};
    const bool has2 = (j < 64);

    for (int kk = 0; kk < DIM; kk += 16) {
        float w0[16], w1[16], w2[16];
        #pragma unroll
        for (int u = 0; u < 16; ++u) {
            const int k = kk + u;
            w0[u] = W_in[k * PCOLS + j];
            w1[u] = W_in[k * PCOLS + 256 + j];
            w2[u] = has2 ? W_in[k * PCOLS + 512 + j] : 0.f;
        }
        #pragma unroll
        for (int r = 0; r < 2; ++r) {
            #pragma unroll
            for (int q = 0; q < 4; ++q) {
                float4 xv = *(const float4*)&xs[r][kk + q * 4];
                const float xa[4] = {xv.x, xv.y, xv.z, xv.w};
                #pragma unroll
                for (int u = 0; u < 4; ++u) {
                    const int uu = q * 4 + u;
                    acc0[r] = fmaf(xa[u], w0[uu], acc0[r]);
                    acc1[r] = fmaf(xa[u], w1[uu], acc1[r]);
                    acc2[r] = fmaf(xa[u], w2[uu], acc2[r]);
                }
            }
        }
    }

    #pragma unroll
    for (int r = 0; r < 2; ++r) {
        const int row = row0 + r;
        if (has2) {
            draw[r][j] = acc0[r];
            bet[row * NST + 192 + j] = acc1[r];
            gam[row * NST + 192 + j] = acc2[r];
        } else {
            bet[row * NST + (j - 64)] = acc0[r];
            gam[row * NST + (j - 64)] = acc1[r];
        }
    }
    __syncthreads();

    float bd = b_dt[j];
    float accd[2] = {bd, bd};
    #pragma unroll 16
    for (int k = 0; k < DTSZ; ++k) {
        float w = W_dt[k * DIM + j];
        #pragma unroll
        for (int r = 0; r < 2; ++r) accd[r] = fmaf(draw[r][k], w, accd[r]);
    }
    #pragma unroll
    for (int r = 0; r < 2; ++r) {
        const int row = row0 + r;
        float sp = softplusf(accd[r]);
        dtp[row * DIM + j]  = sp;
        dtxp[row * DIM + j] = sp * xs[r][j];
    }
}

// ---------------- scan1p: full-sequence scan, one (b,d) per block. 512 blocks x 256.
// No chunking, no rescan, no PS/Q: each chain element touched exactly once.
// Latency armor vs R1's 745 cyc/step: (a) beta/gamma loads batched 8/window and
// prefetched TWO windows ahead (32 loads in flight), (b) dt/dtx staged to LDS once,
// (c) R3-verified 0-conflict transpose-reduction every 16 steps.
__global__ __launch_bounds__(256) void scan1p(
    const float* __restrict__ x,          // [NROWS, DIM]
    const float* __restrict__ alpha_log,  // [DIM, NST]
    const float* __restrict__ delta,      // [DIM]
    const float* __restrict__ bet,        // [NROWS, NST]
    const float* __restrict__ gam,        // [NROWS, NST]
    const float* __restrict__ dtp,        // [NROWS, DIM]
    const float* __restrict__ dtxp,       // [NROWS, DIM]
    float* __restrict__ out)              // [NROWS, DIM]
{
    __shared__ float part[16][NST];       // 16 KB
    __shared__ float dts[LSEQ], dxs[LSEQ];// 2 KB + 2 KB
    const int n = threadIdx.x;
    const int d = blockIdx.x & 255;
    const int b = blockIdx.x >> 8;
    const int rb = b * LSEQ;

    // Stage this d's dt/dtx column for all 512 steps (one-time strided read).
    #pragma unroll
    for (int it = 0; it < 2; ++it) {
        const int l = n + it * 256;
        dts[l] = dtp [(rb + l) * DIM + d];
        dxs[l] = dtxp[(rb + l) * DIM + d];
    }
    const float aln = -__expf(alpha_log[d * NST + n]) * LOG2E;
    const float dv  = delta[d];
    __syncthreads();

    float s = 0.f;
    float be[4][8], ga[4][8];             // 4-buffer rotation, 2 windows ahead
    #pragma unroll
    for (int pw = 0; pw < 2; ++pw) {
        #pragma unroll
        for (int t = 0; t < 8; ++t) {
            be[pw][t] = bet[(rb + pw * 8 + t) * NST + n];
            ga[pw][t] = gam[(rb + pw * 8 + t) * NST + n];
        }
    }

    #pragma unroll 4
    for (int w = 0; w < 64; ++w) {
        const int cur = w & 3;
        const int pf  = (w + 2) & 3;
        if (w + 2 < 64) {                 // issue window w+2 while computing w
            #pragma unroll
            for (int t = 0; t < 8; ++t) {
                be[pf][t] = bet[(rb + (w + 2) * 8 + t) * NST + n];
                ga[pf][t] = gam[(rb + (w + 2) * 8 + t) * NST + n];
            }
        }
        // dt/dtx for this window: broadcast b128 LDS reads
        float4 dta = *(const float4*)&dts[w * 8];
        float4 dtb = *(const float4*)&dts[w * 8 + 4];
        float4 dxa = *(const float4*)&dxs[w * 8];
        float4 dxb = *(const float4*)&dxs[w * 8 + 4];
        const float dtw[8] = {dta.x, dta.y, dta.z, dta.w, dtb.x, dtb.y, dtb.z, dtb.w};
        const float dxw[8] = {dxa.x, dxa.y, dxa.z, dxa.w, dxb.x, dxb.y, dxb.z, dxb.w};

        const int prow = (w & 1) * 8;
        #pragma unroll
        for (int t = 0; t < 8; ++t) {
            float a = fexp2(dtw[t] * aln);
            s = fmaf(a, s, dxw[t] * be[cur][t]);
            part[prow + t][n] = s * ga[cur][t];   // 2-way bank alias: free
        }

        if (w & 1) {                      // every 16 steps: reduce 16 rows x 256
            __syncthreads();
            const int row = n >> 4, m = n & 15, rw = row & 3;
            float sum = 0.f;
            #pragma unroll
            for (int k = 0; k < 16; ++k) {
                int col = m * 16 + ((k + m + 5 * rw) & 15);   // measured 0-conflict
                sum += part[row][col];
            }
            sum += __shfl_xor(sum, 1);
            sum += __shfl_xor(sum, 2);
            sum += __shfl_xor(sum, 4);
            sum += __shfl_xor(sum, 8);
            if (m == 0) {
                const int r = rb + (w >> 1) * 16 + row;
                const int oidx = r * DIM + d;
                out[oidx] = sum + x[oidx] * dv;
            }
            __syncthreads();
        }
    }
}

extern "C" void kernel_launch(void* const* d_in, const int* in_sizes, int n_in,
                              void* d_out, int out_size, void* d_ws, size_t ws_size,
                              hipStream_t stream) {
    const float* x         = (const float*)d_in[0];
    const float* W_in      = (const float*)d_in[1];
    const float* W_dt      = (const float*)d_in[2];
    const float* b_dt      = (const float*)d_in[3];
    const float* alpha_log = (const float*)d_in[4];
    const float* delta     = (const float*)d_in[5];
    float* out = (float*)d_out;

    // Workspace: bet/gam/dtp/dtxp = 4 MB total (PS/Q eliminated)
    float* bet  = (float*)d_ws;
    float* gam  = bet  + NROWS * NST;
    float* dtp  = gam  + NROWS * NST;
    float* dtxp = dtp  + NROWS * DIM;

    proj_kernel<<<NROWS / 2, 256, 0, stream>>>(x, W_in, W_dt, b_dt, bet, gam, dtp, dtxp);
    scan1p<<<BAT * DIM, 256, 0, stream>>>(x, alpha_log, delta, bet, gam, dtp, dtxp, out);
}